// Round 8
// baseline (159.855 us; speedup 1.0000x reference)
//
#include <hip/hip_runtime.h>

#define NS 128
#define NRAYS 8192

typedef unsigned short u16;
typedef unsigned int   u32;
typedef unsigned short u16x8 __attribute__((ext_vector_type(8)));
typedef __bf16 b16x8 __attribute__((ext_vector_type(8)));
typedef float f32x4 __attribute__((ext_vector_type(4)));
typedef _Float16 h16x2 __attribute__((ext_vector_type(2)));
typedef unsigned int u32x4 __attribute__((ext_vector_type(4)));
// align-4 float2: gfx9+ global loads support 4B-aligned dwordx2
typedef float f32x2u __attribute__((ext_vector_type(2), aligned(4)));

__device__ __forceinline__ float clampf(float x, float lo, float hi) {
    return fminf(fmaxf(x, lo), hi);
}

__device__ __forceinline__ u16 f2bf(float f) {
    return __builtin_bit_cast(u16, (__bf16)f);
}

__device__ __forceinline__ u32 pkh(float a, float b) {
    h16x2 v; v[0] = (_Float16)a; v[1] = (_Float16)b;
    return __builtin_bit_cast(u32, v);
}
__device__ __forceinline__ float2 uph(u32 u) {
    h16x2 v = __builtin_bit_cast(h16x2, u);
    return make_float2((float)v[0], (float)v[1]);
}

__device__ __forceinline__ f32x4 mfma_bf16(u16x8 a, u16x8 b, f32x4 c) {
    return __builtin_amdgcn_mfma_f32_16x16x32_bf16(
        __builtin_bit_cast(b16x8, a), __builtin_bit_cast(b16x8, b), c, 0, 0, 0);
}

// swizzled index (u16 units) into a [16][64] bf16 tile, 128B rows.
#define SWZ(r, c) ((((r) * 64) + (c)) ^ (((r) & 7) << 3))

__device__ __forceinline__ void plane_interp(const float* __restrict__ g,
                                             float ca, float cb, float o[3]) {
    float pa = clampf((ca + 1.f) * (0.5f * 127.f), 0.f, 127.f);
    float pb = clampf((cb + 1.f) * (0.5f * 127.f), 0.f, 127.f);
    int la = (int)pa; if (la > 126) la = 126;
    int lb = (int)pb; if (lb > 126) lb = 126;
    float fa = pa - (float)la, fb = pb - (float)lb;
    const float* p = g + la * 128 + lb;
#pragma unroll
    for (int c = 0; c < 3; ++c) {
        const float* q = p + c * 16384;
        f32x2u q0 = *(const f32x2u*)q;          // row la: [lb], [lb+1]
        f32x2u q1 = *(const f32x2u*)(q + 128);  // row la+1
        float top = fmaf(q0[1] - q0[0], fb, q0[0]);
        float bot = fmaf(q1[1] - q1[0], fb, q1[0]);
        o[c] = fmaf(bot - top, fa, top);
    }
}

// ---- prep: pack weight B-fragments (bf16, per-lane layout) into workspace ----
// layout (u16x8 units): [0,256) Bw1 (nb*64+lane), [256,512) Bwc1,
//                       [512,640) Bw2 (ks*64+lane), [640,768) Bwc2
__global__ __launch_bounds__(256)
void prep_weights(const float* __restrict__ w1, const float* __restrict__ wc1,
                  const float* __restrict__ w2, const float* __restrict__ wc2,
                  u16* __restrict__ wsb)
{
    int idx = blockIdx.x * 256 + threadIdx.x;   // 0..6143
    if (idx >= 6144) return;
    int lane = (idx >> 3) & 63;
    int j = idx & 7;
    int c16 = lane & 15, kg = lane >> 4;
    float v;
    if (idx < 2048) {                       // Bw1
        int nb = idx >> 9;
        int k = kg * 8 + j;
        v = w1[k * 64 + nb * 16 + c16];
    } else if (idx < 4096) {                // Bwc1 (zero-pad k>=18)
        int nb = (idx - 2048) >> 9;
        int k = kg * 8 + j;
        v = (k < 18) ? wc1[k * 64 + nb * 16 + c16] : 0.f;
    } else if (idx < 5120) {                // Bw2
        int ks = (idx - 4096) >> 9;
        int k = ks * 32 + kg * 8 + j;
        v = w2[k * 16 + c16];
    } else {                                // Bwc2 (N padded to 16)
        int ks = (idx - 5120) >> 9;
        int k = ks * 32 + kg * 8 + j;
        v = (c16 < 3) ? wc2[k * 3 + c16] : 0.f;
    }
    wsb[idx] = f2bf(v);
}

// block = 1 ray, 2 waves; wave wv handles chunks wv*4 .. wv*4+3 (16 samples each)
// with 1-deep gather prefetch: issue chunk c+1's float2 loads before chunk c's GEMMs.
__global__ __launch_bounds__(128)
void nerf_mfma(const float* __restrict__ rays_o,
               const float* __restrict__ rays_d,
               const float* __restrict__ bg_color,
               const float* __restrict__ plane01,
               const float* __restrict__ plane02,
               const float* __restrict__ plane12,
               const float* __restrict__ features,
               const float* __restrict__ w1, const float* __restrict__ b1,
               const float* __restrict__ w2, const float* __restrict__ b2,
               const float* __restrict__ wc1, const float* __restrict__ bc1,
               const float* __restrict__ wc2, const float* __restrict__ bc2,
               const float* __restrict__ aabb,
               float* __restrict__ out,
               const u16* __restrict__ wsb, int use_ws)
{
    __shared__ __align__(16) u32x4 s_cw[128];           // trilinear corner weights (f16x2 x4)
    __shared__ u32   s_fb[128];                         // cell base offsets
    __shared__ __align__(16) u16  s_trans[2][16 * 64];  // per-wave h/h2 transpose tile
    __shared__ __align__(16) u16  s_cin[2][16 * 64];    // per-wave color-MLP A tile
    __shared__ float s_tau[128];
    __shared__ float s_rgb[3][128];

    const int tid  = threadIdx.x;
    const int wv   = tid >> 6;
    const int lane = tid & 63;
    const int c16  = lane & 15;
    const int kg   = lane >> 4;
    const int ray  = blockIdx.x;

    // ---- weight B-fragments (VGPR-resident) ----
    u16x8 Bw1[4], Bwc1[4], Bw2[2], Bwc2[2];
    if (use_ws) {
        const u16x8* wf = (const u16x8*)wsb;
#pragma unroll
        for (int nb = 0; nb < 4; ++nb) {
            Bw1[nb]  = wf[nb * 64 + lane];
            Bwc1[nb] = wf[256 + nb * 64 + lane];
        }
#pragma unroll
        for (int ks = 0; ks < 2; ++ks) {
            Bw2[ks]  = wf[512 + ks * 64 + lane];
            Bwc2[ks] = wf[640 + ks * 64 + lane];
        }
    } else {
#pragma unroll
        for (int nb = 0; nb < 4; ++nb)
#pragma unroll
            for (int j = 0; j < 8; ++j) {
                int k = kg * 8 + j;
                Bw1[nb][j]  = f2bf(w1[k * 64 + nb * 16 + c16]);
                Bwc1[nb][j] = f2bf(k < 18 ? wc1[k * 64 + nb * 16 + c16] : 0.f);
            }
#pragma unroll
        for (int ks = 0; ks < 2; ++ks)
#pragma unroll
            for (int j = 0; j < 8; ++j) {
                int k = ks * 32 + kg * 8 + j;
                Bw2[ks][j]  = f2bf(w2[k * 16 + c16]);
                Bwc2[ks][j] = f2bf(c16 < 3 ? wc2[k * 3 + c16] : 0.f);
            }
    }
    float b1v[4], bc1v[4];
#pragma unroll
    for (int nb = 0; nb < 4; ++nb) {
        b1v[nb]  = b1[nb * 16 + c16];
        bc1v[nb] = bc1[nb * 16 + c16];
    }
    float b2v  = b2[c16];
    float bc2v = (c16 < 3) ? bc2[c16] : 0.f;

    // ---- per-ray setup ----
    float ox = rays_o[ray * 3 + 0], oy = rays_o[ray * 3 + 1], oz = rays_o[ray * 3 + 2];
    float dx = rays_d[ray * 3 + 0], dy = rays_d[ray * 3 + 1], dz = rays_d[ray * 3 + 2];
    float rn = rsqrtf(dx * dx + dy * dy + dz * dz);
    dx *= rn; dy *= rn; dz *= rn;

    float lo0 = aabb[0], lo1 = aabb[1], lo2 = aabb[2];
    float hi0 = aabb[3], hi1 = aabb[4], hi2 = aabb[5];

    float invx = 1.f / dx, invy = 1.f / dy, invz = 1.f / dz;
    float tx0 = (lo0 - ox) * invx, tx1 = (hi0 - ox) * invx;
    float ty0 = (lo1 - oy) * invy, ty1 = (hi1 - oy) * invy;
    float tz0 = (lo2 - oz) * invz, tz1 = (hi2 - oz) * invz;
    float tnear = fmaxf(fmaxf(fminf(tx0, tx1), fminf(ty0, ty1)), fminf(tz0, tz1));
    tnear = fmaxf(tnear, 0.f);
    float tfar = fminf(fminf(fmaxf(tx0, tx1), fmaxf(ty0, ty1)), fmaxf(tz0, tz1));
    tfar = fmaxf(tfar, tnear);
    float delta = (tfar - tnear) * (1.f / (float)NS);

    // ---- coordinate phase: 128 threads, 1 sample each ----
    {
        int s = tid;
        float t = tnear + delta * ((float)s + 0.5f);
        float px = ox + dx * t, py = oy + dy * t, pz = oz + dz * t;
        px = (px - lo0) * (2.f / (hi0 - lo0)) - 1.f;
        py = (py - lo1) * (2.f / (hi1 - lo1)) - 1.f;
        pz = (pz - lo2) * (2.f / (hi2 - lo2)) - 1.f;

        float p01[3], p02[3], p12[3];
        plane_interp(plane01, px, py, p01);
        plane_interp(plane02, px, pz, p02);
        plane_interp(plane12, py, pz, p12);
        float gx = p01[0] * p02[0] * p12[0];
        float gy = p01[1] * p02[1] * p12[1];
        float gz = p01[2] * p02[2] * p12[2];

        float qx = clampf((gx + 1.f) * (0.5f * 63.f), 0.f, 63.f);
        float qy = clampf((gy + 1.f) * (0.5f * 63.f), 0.f, 63.f);
        float qz = clampf((gz + 1.f) * (0.5f * 63.f), 0.f, 63.f);
        int ixg = (int)qx; if (ixg > 62) ixg = 62;
        int iyg = (int)qy; if (iyg > 62) iyg = 62;
        int izg = (int)qz; if (izg > 62) izg = 62;
        float fx = qx - (float)ixg, fy = qy - (float)iyg, fz = qz - (float)izg;
        float wx0 = 1.f - fx, wy0 = 1.f - fy, wz0 = 1.f - fz;
        u32x4 cw;
        cw[0] = pkh(wx0 * wy0 * wz0, wx0 * wy0 * fz);
        cw[1] = pkh(wx0 * fy  * wz0, wx0 * fy  * fz);
        cw[2] = pkh(fx  * wy0 * wz0, fx  * wy0 * fz);
        cw[3] = pkh(fx  * fy  * wz0, fx  * fy  * fz);
        s_cw[s] = cw;
        s_fb[s] = (u32)(ixg * 4096 + iyg * 64 + izg);
    }

    // ---- init this wave's cin tile: zero (pads k=18..31), dirs in cols 0..2 ----
    {
        u32x4 z4 = {0, 0, 0, 0};
        u32x4* zp = (u32x4*)s_cin[wv];
#pragma unroll
        for (int i = lane; i < 128; i += 64) zp[i] = z4;
        if (lane < 16) {
            s_cin[wv][SWZ(lane, 0)] = f2bf(dx);
            s_cin[wv][SWZ(lane, 1)] = f2bf(dy);
            s_cin[wv][SWZ(lane, 2)] = f2bf(dz);
        }
    }
    __syncthreads();

    // ---- 4 chunks of 16 samples per wave, 1-deep gather prefetch ----
    f32x2u pf[8][4];     // 8 channels x 4 corner-pairs, single register set
    u32x4 cw_cur;

#define ISSUE_GATHER(fbv)                                              \
    {                                                                  \
        const float* fb_ = features + (fbv);                           \
        _Pragma("unroll")                                              \
        for (int j = 0; j < 8; ++j) {                                  \
            const float* f = fb_ + (size_t)(kg * 8 + j) * 262144;      \
            pf[j][0] = *(const f32x2u*)(f);                            \
            pf[j][1] = *(const f32x2u*)(f + 64);                       \
            pf[j][2] = *(const f32x2u*)(f + 4096);                     \
            pf[j][3] = *(const f32x2u*)(f + 4160);                     \
        }                                                              \
    }

    {
        const int c0 = wv * 4;
        cw_cur = s_cw[c0 * 16 + c16];
        u32 fb0 = s_fb[c0 * 16 + c16];
        ISSUE_GATHER(fb0);
    }

#pragma unroll 1
    for (int cc = 0; cc < 4; ++cc) {
        const int c = wv * 4 + cc;

        float2 w0p = uph(cw_cur[0]);
        float2 w1p = uph(cw_cur[1]);
        float2 w2p = uph(cw_cur[2]);
        float2 w3p = uph(cw_cur[3]);

        // combine gathered values -> A1 fragment (consumes pf)
        u16x8 a1;
#pragma unroll
        for (int j = 0; j < 8; ++j) {
            float v = fmaf(w0p.x, pf[j][0][0], fmaf(w0p.y, pf[j][0][1],
                      fmaf(w1p.x, pf[j][1][0], fmaf(w1p.y, pf[j][1][1],
                      fmaf(w2p.x, pf[j][2][0], fmaf(w2p.y, pf[j][2][1],
                      fmaf(w3p.x, pf[j][3][0], w3p.y * pf[j][3][1])))))));
            a1[j] = f2bf(v);
        }

        // prefetch next chunk's gathers (overlap with GEMM chain below)
        if (cc < 3) {
            cw_cur = s_cw[(c + 1) * 16 + c16];
            u32 fbn = s_fb[(c + 1) * 16 + c16];
            ISSUE_GATHER(fbn);
        }

        // GEMM1: h[16x64] = A1 @ w1 + b1
        f32x4 acc[4];
#pragma unroll
        for (int nb = 0; nb < 4; ++nb) {
            f32x4 ci; ci[0] = ci[1] = ci[2] = ci[3] = b1v[nb];
            acc[nb] = mfma_bf16(a1, Bw1[nb], ci);
        }
#pragma unroll
        for (int nb = 0; nb < 4; ++nb)
#pragma unroll
            for (int q = 0; q < 4; ++q) {
                int r = kg * 4 + q;
                s_trans[wv][SWZ(r, nb * 16 + c16)] = f2bf(fmaxf(acc[nb][q], 0.f));
            }

        // GEMM2: so[16x16] = relu(h) @ w2 + b2
        f32x4 acc2; acc2[0] = acc2[1] = acc2[2] = acc2[3] = b2v;
#pragma unroll
        for (int ks = 0; ks < 2; ++ks) {
            u16x8 a2 = *(const u16x8*)&s_trans[wv][SWZ(c16, ks * 32 + kg * 8)];
            acc2 = mfma_bf16(a2, Bw2[ks], acc2);
        }

        // density (col 0) -> tau ; so[1:16] -> cin cols 3..17
        if (c16 == 0) {
#pragma unroll
            for (int q = 0; q < 4; ++q) {
                float d = __expf(clampf(acc2[q], -15.f, 15.f));
                s_tau[c * 16 + kg * 4 + q] = d * delta;
            }
        } else {
#pragma unroll
            for (int q = 0; q < 4; ++q) {
                int r = kg * 4 + q;
                s_cin[wv][SWZ(r, c16 + 2)] = f2bf(acc2[q]);
            }
        }

        // GEMM3: h2[16x64] = cin @ wc1 + bc1
        u16x8 a3 = *(const u16x8*)&s_cin[wv][SWZ(c16, kg * 8)];
        f32x4 acc3[4];
#pragma unroll
        for (int nb = 0; nb < 4; ++nb) {
            f32x4 ci; ci[0] = ci[1] = ci[2] = ci[3] = bc1v[nb];
            acc3[nb] = mfma_bf16(a3, Bwc1[nb], ci);
        }
#pragma unroll
        for (int nb = 0; nb < 4; ++nb)
#pragma unroll
            for (int q = 0; q < 4; ++q) {
                int r = kg * 4 + q;
                s_trans[wv][SWZ(r, nb * 16 + c16)] = f2bf(fmaxf(acc3[nb][q], 0.f));
            }

        // GEMM4: rgb[16x3] = relu(h2) @ wc2 + bc2
        f32x4 acc4; acc4[0] = acc4[1] = acc4[2] = acc4[3] = bc2v;
#pragma unroll
        for (int ks = 0; ks < 2; ++ks) {
            u16x8 a4 = *(const u16x8*)&s_trans[wv][SWZ(c16, ks * 32 + kg * 8)];
            acc4 = mfma_bf16(a4, Bwc2[ks], acc4);
        }
        if (c16 < 3) {
#pragma unroll
            for (int q = 0; q < 4; ++q) {
                float sg = 1.f / (1.f + __expf(-acc4[q]));
                s_rgb[c16][c * 16 + kg * 4 + q] = sg;
            }
        }
    }
#undef ISSUE_GATHER
    __syncthreads();

    // ---- integration on wave 0 (2 samples per lane) ----
    if (wv == 0) {
        float t0 = s_tau[lane];
        float t1 = s_tau[64 + lane];
        float x0 = t0, x1 = t1;
#pragma unroll
        for (int off = 1; off < 64; off <<= 1) {
            float y = __shfl_up(x0, off);
            if (lane >= off) x0 += y;
        }
        float tot0 = __shfl(x0, 63);
#pragma unroll
        for (int off = 1; off < 64; off <<= 1) {
            float y = __shfl_up(x1, off);
            if (lane >= off) x1 += y;
        }
        x1 += tot0;

        float w0 = __expf(t0 - x0) * (1.f - __expf(-t0));
        float w1s = __expf(t1 - x1) * (1.f - __expf(-t1));

        float v0 = w0 * s_rgb[0][lane] + w1s * s_rgb[0][64 + lane];
        float v1 = w0 * s_rgb[1][lane] + w1s * s_rgb[1][64 + lane];
        float v2 = w0 * s_rgb[2][lane] + w1s * s_rgb[2][64 + lane];
        float v3 = w0 + w1s;
#pragma unroll
        for (int off = 32; off; off >>= 1) {
            v0 += __shfl_xor(v0, off);
            v1 += __shfl_xor(v1, off);
            v2 += __shfl_xor(v2, off);
            v3 += __shfl_xor(v3, off);
        }
        if (lane == 0) {
            float bg = bg_color[0];
            out[ray * 3 + 0] = v0 + (1.f - v3) * bg;
            out[ray * 3 + 1] = v1 + (1.f - v3) * bg;
            out[ray * 3 + 2] = v2 + (1.f - v3) * bg;
        }
    }
}

extern "C" void kernel_launch(void* const* d_in, const int* in_sizes, int n_in,
                              void* d_out, int out_size, void* d_ws, size_t ws_size,
                              hipStream_t stream) {
    const float* rays_o  = (const float*)d_in[0];
    const float* rays_d  = (const float*)d_in[1];
    const float* bg      = (const float*)d_in[2];
    const float* p01     = (const float*)d_in[3];
    const float* p02     = (const float*)d_in[4];
    const float* p12     = (const float*)d_in[5];
    const float* feats   = (const float*)d_in[6];
    const float* w1      = (const float*)d_in[7];
    const float* b1      = (const float*)d_in[8];
    const float* w2      = (const float*)d_in[9];
    const float* b2      = (const float*)d_in[10];
    const float* wc1     = (const float*)d_in[11];
    const float* bc1     = (const float*)d_in[12];
    const float* wc2     = (const float*)d_in[13];
    const float* bc2     = (const float*)d_in[14];
    const float* aabb    = (const float*)d_in[15];
    float* out = (float*)d_out;

    const int use_ws = (ws_size >= 6144 * sizeof(u16)) ? 1 : 0;
    u16* wsb = (u16*)d_ws;
    if (use_ws) {
        prep_weights<<<24, 256, 0, stream>>>(w1, wc1, w2, wc2, wsb);
    }
    nerf_mfma<<<NRAYS, 128, 0, stream>>>(rays_o, rays_d, bg, p01, p02, p12, feats,
                                         w1, b1, w2, b2, wc1, bc1, wc2, bc2, aabb, out,
                                         wsb, use_ws);
}

// Round 9
// 145.123 us; speedup vs baseline: 1.1015x; 1.1015x over previous
//
#include <hip/hip_runtime.h>

#define NS 128
#define NRAYS 8192

typedef unsigned short u16;
typedef unsigned int   u32;
typedef unsigned short u16x8 __attribute__((ext_vector_type(8)));
typedef __bf16 b16x8 __attribute__((ext_vector_type(8)));
typedef float f32x4 __attribute__((ext_vector_type(4)));
typedef _Float16 h16x2 __attribute__((ext_vector_type(2)));
typedef unsigned int u32x4 __attribute__((ext_vector_type(4)));
typedef float f32x2u __attribute__((ext_vector_type(2), aligned(4)));

__device__ __forceinline__ float clampf(float x, float lo, float hi) {
    return fminf(fmaxf(x, lo), hi);
}

__device__ __forceinline__ u16 f2bf(float f) {
    return __builtin_bit_cast(u16, (__bf16)f);
}

// pack two f32 -> bf16 pair in one u32 (lo in bits 0-15)
__device__ __forceinline__ u32 pk2bf(float lo, float hi) {
    return (u32)f2bf(lo) | ((u32)f2bf(hi) << 16);
}

__device__ __forceinline__ u32 pkh(float a, float b) {
    h16x2 v; v[0] = (_Float16)a; v[1] = (_Float16)b;
    return __builtin_bit_cast(u32, v);
}
__device__ __forceinline__ float2 uph(u32 u) {
    h16x2 v = __builtin_bit_cast(h16x2, u);
    return make_float2((float)v[0], (float)v[1]);
}

__device__ __forceinline__ f32x4 mfma_bf16(u16x8 a, u16x8 b, f32x4 c) {
    return __builtin_amdgcn_mfma_f32_16x16x32_bf16(
        __builtin_bit_cast(b16x8, a), __builtin_bit_cast(b16x8, b), c, 0, 0, 0);
}

__device__ __forceinline__ void plane_interp(const float* __restrict__ g,
                                             float ca, float cb, float o[3]) {
    float pa = clampf((ca + 1.f) * (0.5f * 127.f), 0.f, 127.f);
    float pb = clampf((cb + 1.f) * (0.5f * 127.f), 0.f, 127.f);
    int la = (int)pa; if (la > 126) la = 126;
    int lb = (int)pb; if (lb > 126) lb = 126;
    float fa = pa - (float)la, fb = pb - (float)lb;
    const float* p = g + la * 128 + lb;
#pragma unroll
    for (int c = 0; c < 3; ++c) {
        const float* q = p + c * 16384;
        f32x2u q0 = *(const f32x2u*)q;
        f32x2u q1 = *(const f32x2u*)(q + 128);
        float top = fmaf(q0[1] - q0[0], fb, q0[0]);
        float bot = fmaf(q1[1] - q1[0], fb, q1[0]);
        o[c] = fmaf(bot - top, fa, top);
    }
}

// ---- prep: pack weight A-fragments (bf16, per-lane layout) into workspace ----
// A-frag value[lane][j] = M[k = (lane>>4)*8+j][idx = lane&15] (identical lane
// layout as the old B-frags). wc1 rows are PERMUTED to cin' = [so0(zeroed),
// so1..so15, dx,dy,dz, 0-pad] ordering.
// layout (u16x8 units): [0,256) AW1 (nb*64+lane), [256,512) AWc1',
//                       [512,640) AW2 (ks*64+lane), [640,768) AWc2
__global__ __launch_bounds__(256)
void prep_weights(const float* __restrict__ w1, const float* __restrict__ wc1,
                  const float* __restrict__ w2, const float* __restrict__ wc2,
                  u16* __restrict__ wsb)
{
    int idx = blockIdx.x * 256 + threadIdx.x;   // 0..6143
    if (idx >= 6144) return;
    int lane = (idx >> 3) & 63;
    int j = idx & 7;
    int c16 = lane & 15, kg = lane >> 4;
    float v;
    if (idx < 2048) {                       // AW1 (W1^T blocks)
        int nb = idx >> 9;
        int k = kg * 8 + j;
        v = w1[k * 64 + nb * 16 + c16];
    } else if (idx < 4096) {                // AWc1' (permuted rows)
        int nb = (idx - 2048) >> 9;
        int k = kg * 8 + j;                 // cin' row
        if (k == 0)       v = 0.f;                                 // so0 excluded
        else if (k < 16)  v = wc1[(k + 2) * 64 + nb * 16 + c16];   // so[k]
        else if (k < 19)  v = wc1[(k - 16) * 64 + nb * 16 + c16];  // dir
        else              v = 0.f;
    } else if (idx < 5120) {                // AW2
        int ks = (idx - 4096) >> 9;
        int k = ks * 32 + kg * 8 + j;
        v = w2[k * 16 + c16];
    } else {                                // AWc2 (M padded 3->16)
        int ks = (idx - 5120) >> 9;
        int k = ks * 32 + kg * 8 + j;
        v = (c16 < 3) ? wc2[k * 3 + c16] : 0.f;
    }
    wsb[idx] = f2bf(v);
}

// relu C-regs and pack to 2x bf16-pair words
#define RELUPACK(ACC, PA, PB) {                                        \
    float r0_ = fmaxf((ACC)[0], 0.f), r1_ = fmaxf((ACC)[1], 0.f);      \
    float r2_ = fmaxf((ACC)[2], 0.f), r3_ = fmaxf((ACC)[3], 0.f);      \
    PA = pk2bf(r0_, r1_); PB = pk2bf(r2_, r3_); }

// transpose h^T C-regs -> next-GEMM B-fragment (one K=32 slice) via 4-lane
// exchange: dest lane (c16,kg) word w needs pair (w&1) of P[nb] from lane
// (c16, kg'=(2kg+(w>>1))&3), nb = (kg<2) ? lo : hi.
#define HTRANS(PLA, PLB, PHA, PHB, OUT) {                              \
    int a0_ = __shfl((int)(PLA), sA), a1_ = __shfl((int)(PLB), sA);    \
    int a2_ = __shfl((int)(PLA), sB), a3_ = __shfl((int)(PLB), sB);    \
    int b0_ = __shfl((int)(PHA), sA), b1_ = __shfl((int)(PHB), sA);    \
    int b2_ = __shfl((int)(PHA), sB), b3_ = __shfl((int)(PHB), sB);    \
    u32x4 t_;                                                          \
    t_[0] = kglo ? (u32)a0_ : (u32)b0_;                                \
    t_[1] = kglo ? (u32)a1_ : (u32)b1_;                                \
    t_[2] = kglo ? (u32)a2_ : (u32)b2_;                                \
    t_[3] = kglo ? (u32)a3_ : (u32)b3_;                                \
    OUT = __builtin_bit_cast(u16x8, t_); }

// block = 1 ray, 4 waves; wave wv handles chunks {2wv, 2wv+1} of 16 samples.
// All GEMMs operand-swapped (out^T = W^T @ in^T): weights are A-operands,
// activations stay in registers; inter-layer transposes are ds_bpermute
// shuffles — zero LDS tiles, zero barriers in the chunk loop.
__global__ __launch_bounds__(256)
void nerf_mfma(const float* __restrict__ rays_o,
               const float* __restrict__ rays_d,
               const float* __restrict__ bg_color,
               const float* __restrict__ plane01,
               const float* __restrict__ plane02,
               const float* __restrict__ plane12,
               const float* __restrict__ features,
               const float* __restrict__ w1, const float* __restrict__ b1,
               const float* __restrict__ w2, const float* __restrict__ b2,
               const float* __restrict__ wc1, const float* __restrict__ bc1,
               const float* __restrict__ wc2, const float* __restrict__ bc2,
               const float* __restrict__ aabb,
               float* __restrict__ out,
               const u16* __restrict__ wsb, int use_ws)
{
    __shared__ __align__(16) u32x4 s_cw[128];   // trilinear corner weights
    __shared__ u32   s_fb[128];                 // cell base offsets
    __shared__ float s_tau[128];
    __shared__ float s_rgb[3][128];

    const int tid  = threadIdx.x;
    const int wv   = tid >> 6;
    const int lane = tid & 63;
    const int c16  = lane & 15;
    const int kg   = lane >> 4;
    const int ray  = blockIdx.x;
    const int sA   = c16 + 16 * ((2 * kg) & 3);
    const int sB   = c16 + 16 * ((2 * kg + 1) & 3);
    const bool kglo = (kg < 2);

    // ---- weight A-fragments (VGPR-resident) ----
    u16x8 AW1[4], AWc1[4], AW2[2], AWc2[2];
    if (use_ws) {
        const u16x8* wf = (const u16x8*)wsb;
#pragma unroll
        for (int nb = 0; nb < 4; ++nb) {
            AW1[nb]  = wf[nb * 64 + lane];
            AWc1[nb] = wf[256 + nb * 64 + lane];
        }
#pragma unroll
        for (int ks = 0; ks < 2; ++ks) {
            AW2[ks]  = wf[512 + ks * 64 + lane];
            AWc2[ks] = wf[640 + ks * 64 + lane];
        }
    } else {
#pragma unroll
        for (int nb = 0; nb < 4; ++nb)
#pragma unroll
            for (int j = 0; j < 8; ++j) {
                int k = kg * 8 + j;
                AW1[nb][j] = f2bf(w1[k * 64 + nb * 16 + c16]);
                float v;
                if (k == 0)       v = 0.f;
                else if (k < 16)  v = wc1[(k + 2) * 64 + nb * 16 + c16];
                else if (k < 19)  v = wc1[(k - 16) * 64 + nb * 16 + c16];
                else              v = 0.f;
                AWc1[nb][j] = f2bf(v);
            }
#pragma unroll
        for (int ks = 0; ks < 2; ++ks)
#pragma unroll
            for (int j = 0; j < 8; ++j) {
                int k = ks * 32 + kg * 8 + j;
                AW2[ks][j]  = f2bf(w2[k * 16 + c16]);
                AWc2[ks][j] = f2bf(c16 < 3 ? wc2[k * 3 + c16] : 0.f);
            }
    }
    // biases as MFMA C-operands: C row = kg*4+q -> bias[base + kg*4+q]
    f32x4 b1v4[4], bc1v4[4];
#pragma unroll
    for (int nb = 0; nb < 4; ++nb) {
        b1v4[nb]  = *(const f32x4*)(b1  + nb * 16 + kg * 4);
        bc1v4[nb] = *(const f32x4*)(bc1 + nb * 16 + kg * 4);
    }
    f32x4 b2v4 = *(const f32x4*)(b2 + kg * 4);
    f32x4 bc2v4; bc2v4[0] = bc2v4[1] = bc2v4[2] = bc2v4[3] = 0.f;
    if (kg == 0) { bc2v4[0] = bc2[0]; bc2v4[1] = bc2[1]; bc2v4[2] = bc2[2]; }

    // ---- per-ray setup ----
    float ox = rays_o[ray * 3 + 0], oy = rays_o[ray * 3 + 1], oz = rays_o[ray * 3 + 2];
    float dx = rays_d[ray * 3 + 0], dy = rays_d[ray * 3 + 1], dz = rays_d[ray * 3 + 2];
    float rn = rsqrtf(dx * dx + dy * dy + dz * dz);
    dx *= rn; dy *= rn; dz *= rn;

    float lo0 = aabb[0], lo1 = aabb[1], lo2 = aabb[2];
    float hi0 = aabb[3], hi1 = aabb[4], hi2 = aabb[5];

    float invx = 1.f / dx, invy = 1.f / dy, invz = 1.f / dz;
    float tx0 = (lo0 - ox) * invx, tx1 = (hi0 - ox) * invx;
    float ty0 = (lo1 - oy) * invy, ty1 = (hi1 - oy) * invy;
    float tz0 = (lo2 - oz) * invz, tz1 = (hi2 - oz) * invz;
    float tnear = fmaxf(fmaxf(fminf(tx0, tx1), fminf(ty0, ty1)), fminf(tz0, tz1));
    tnear = fmaxf(tnear, 0.f);
    float tfar = fminf(fminf(fmaxf(tx0, tx1), fmaxf(ty0, ty1)), fmaxf(tz0, tz1));
    tfar = fmaxf(tfar, tnear);
    float delta = (tfar - tnear) * (1.f / (float)NS);

    // dir constants for cin' rows 16..18 (kg==2 k-slice)
    const u32 dir01 = pk2bf(dx, dy);
    const u32 dir2z = pk2bf(dz, 0.f);

    // ---- coordinate phase: threads 0..127 compute 1 sample each ----
    if (tid < 128) {
        int s = tid;
        float t = tnear + delta * ((float)s + 0.5f);
        float px = ox + dx * t, py = oy + dy * t, pz = oz + dz * t;
        px = (px - lo0) * (2.f / (hi0 - lo0)) - 1.f;
        py = (py - lo1) * (2.f / (hi1 - lo1)) - 1.f;
        pz = (pz - lo2) * (2.f / (hi2 - lo2)) - 1.f;

        float p01[3], p02[3], p12[3];
        plane_interp(plane01, px, py, p01);
        plane_interp(plane02, px, pz, p02);
        plane_interp(plane12, py, pz, p12);
        float gx = p01[0] * p02[0] * p12[0];
        float gy = p01[1] * p02[1] * p12[1];
        float gz = p01[2] * p02[2] * p12[2];

        float qx = clampf((gx + 1.f) * (0.5f * 63.f), 0.f, 63.f);
        float qy = clampf((gy + 1.f) * (0.5f * 63.f), 0.f, 63.f);
        float qz = clampf((gz + 1.f) * (0.5f * 63.f), 0.f, 63.f);
        int ixg = (int)qx; if (ixg > 62) ixg = 62;
        int iyg = (int)qy; if (iyg > 62) iyg = 62;
        int izg = (int)qz; if (izg > 62) izg = 62;
        float fx = qx - (float)ixg, fy = qy - (float)iyg, fz = qz - (float)izg;
        float wx0 = 1.f - fx, wy0 = 1.f - fy, wz0 = 1.f - fz;
        u32x4 cw;
        cw[0] = pkh(wx0 * wy0 * wz0, wx0 * wy0 * fz);
        cw[1] = pkh(wx0 * fy  * wz0, wx0 * fy  * fz);
        cw[2] = pkh(fx  * wy0 * wz0, fx  * wy0 * fz);
        cw[3] = pkh(fx  * fy  * wz0, fx  * fy  * fz);
        s_cw[s] = cw;
        s_fb[s] = (u32)(ixg * 4096 + iyg * 64 + izg);
    }
    __syncthreads();

    // ---- 2 chunks of 16 samples per wave ----
#pragma unroll
    for (int cc = 0; cc < 2; ++cc) {
        const int c = wv * 2 + cc;
        u32x4 cwp = s_cw[c * 16 + c16];
        u32 fb = s_fb[c * 16 + c16];
        float2 w0p = uph(cwp[0]);
        float2 w1p = uph(cwp[1]);
        float2 w2p = uph(cwp[2]);
        float2 w3p = uph(cwp[3]);
        const float* fbase = features + fb;

        // gather + trilinear combine -> B-operand for GEMM1 (col=sample, k=channel)
        u32x4 a1v;
#pragma unroll
        for (int jj = 0; jj < 4; ++jj) {
            float vv[2];
#pragma unroll
            for (int h = 0; h < 2; ++h) {
                const float* f = fbase + (size_t)(kg * 8 + jj * 2 + h) * 262144;
                f32x2u q0 = *(const f32x2u*)(f);
                f32x2u q1 = *(const f32x2u*)(f + 64);
                f32x2u q2 = *(const f32x2u*)(f + 4096);
                f32x2u q3 = *(const f32x2u*)(f + 4160);
                vv[h] = fmaf(w0p.x, q0[0], fmaf(w0p.y, q0[1],
                        fmaf(w1p.x, q1[0], fmaf(w1p.y, q1[1],
                        fmaf(w2p.x, q2[0], fmaf(w2p.y, q2[1],
                        fmaf(w3p.x, q3[0], w3p.y * q3[1])))))));
            }
            a1v[jj] = pk2bf(vv[0], vv[1]);
        }
        u16x8 a1 = __builtin_bit_cast(u16x8, a1v);

        // GEMM1 swapped: h^T = W1^T @ A1^T  (bias free via C-operand)
        f32x4 g0 = mfma_bf16(AW1[0], a1, b1v4[0]);
        f32x4 g1 = mfma_bf16(AW1[1], a1, b1v4[1]);
        f32x4 g2 = mfma_bf16(AW1[2], a1, b1v4[2]);
        f32x4 g3 = mfma_bf16(AW1[3], a1, b1v4[3]);

        u32 P0a, P0b, P1a, P1b, P2a, P2b, P3a, P3b;
        RELUPACK(g0, P0a, P0b); RELUPACK(g1, P1a, P1b);
        RELUPACK(g2, P2a, P2b); RELUPACK(g3, P3a, P3b);

        u16x8 B2_0, B2_1;
        HTRANS(P0a, P0b, P1a, P1b, B2_0);   // k = 0..31  (features)
        HTRANS(P2a, P2b, P3a, P3b, B2_1);   // k = 32..63

        // GEMM2 swapped: so^T = W2^T @ h^T
        f32x4 so = mfma_bf16(AW2[0], B2_0, b2v4);
        so = mfma_bf16(AW2[1], B2_1, so);

        // density (so row 0 lives in kg==0, q==0)
        float dens = __expf(clampf(so[0], -15.f, 15.f));
        if (kg == 0) s_tau[c * 16 + c16] = dens * delta;

        // cin'^T B-fragment: rows 0..15 = so (shuffle), 16..18 = dir, 19..31 = 0
        u32 Q0 = pk2bf(so[0], so[1]);
        u32 Q1 = pk2bf(so[2], so[3]);
        u32x4 ct;
        ct[0] = (u32)__shfl((int)Q0, sA);
        ct[1] = (u32)__shfl((int)Q1, sA);
        ct[2] = (u32)__shfl((int)Q0, sB);
        ct[3] = (u32)__shfl((int)Q1, sB);
        if (kg == 2) { ct[0] = dir01; ct[1] = dir2z; ct[2] = 0u; ct[3] = 0u; }
        if (kg == 3) { ct[0] = 0u; ct[1] = 0u; ct[2] = 0u; ct[3] = 0u; }
        u16x8 bcin = __builtin_bit_cast(u16x8, ct);

        // GEMM3 swapped: h2^T = Wc1'^T @ cin'^T  (K=32, single k-step)
        f32x4 h0 = mfma_bf16(AWc1[0], bcin, bc1v4[0]);
        f32x4 h1 = mfma_bf16(AWc1[1], bcin, bc1v4[1]);
        f32x4 h2 = mfma_bf16(AWc1[2], bcin, bc1v4[2]);
        f32x4 h3 = mfma_bf16(AWc1[3], bcin, bc1v4[3]);

        RELUPACK(h0, P0a, P0b); RELUPACK(h1, P1a, P1b);
        RELUPACK(h2, P2a, P2b); RELUPACK(h3, P3a, P3b);

        u16x8 B4_0, B4_1;
        HTRANS(P0a, P0b, P1a, P1b, B4_0);
        HTRANS(P2a, P2b, P3a, P3b, B4_1);

        // GEMM4 swapped: rgb^T = Wc2^T @ h2^T
        f32x4 cacc = mfma_bf16(AWc2[0], B4_0, bc2v4);
        cacc = mfma_bf16(AWc2[1], B4_1, cacc);

        if (kg == 0) {
            int si = c * 16 + c16;
            s_rgb[0][si] = 1.f / (1.f + __expf(-cacc[0]));
            s_rgb[1][si] = 1.f / (1.f + __expf(-cacc[1]));
            s_rgb[2][si] = 1.f / (1.f + __expf(-cacc[2]));
        }
    }
    __syncthreads();

    // ---- integration on wave 0 (2 samples per lane) ----
    if (wv == 0) {
        float t0 = s_tau[lane];
        float t1 = s_tau[64 + lane];
        float x0 = t0, x1 = t1;
#pragma unroll
        for (int off = 1; off < 64; off <<= 1) {
            float y = __shfl_up(x0, off);
            if (lane >= off) x0 += y;
        }
        float tot0 = __shfl(x0, 63);
#pragma unroll
        for (int off = 1; off < 64; off <<= 1) {
            float y = __shfl_up(x1, off);
            if (lane >= off) x1 += y;
        }
        x1 += tot0;

        float w0 = __expf(t0 - x0) * (1.f - __expf(-t0));
        float w1s = __expf(t1 - x1) * (1.f - __expf(-t1));

        float v0 = w0 * s_rgb[0][lane] + w1s * s_rgb[0][64 + lane];
        float v1 = w0 * s_rgb[1][lane] + w1s * s_rgb[1][64 + lane];
        float v2 = w0 * s_rgb[2][lane] + w1s * s_rgb[2][64 + lane];
        float v3 = w0 + w1s;
#pragma unroll
        for (int off = 32; off; off >>= 1) {
            v0 += __shfl_xor(v0, off);
            v1 += __shfl_xor(v1, off);
            v2 += __shfl_xor(v2, off);
            v3 += __shfl_xor(v3, off);
        }
        if (lane == 0) {
            float bg = bg_color[0];
            out[ray * 3 + 0] = v0 + (1.f - v3) * bg;
            out[ray * 3 + 1] = v1 + (1.f - v3) * bg;
            out[ray * 3 + 2] = v2 + (1.f - v3) * bg;
        }
    }
}

extern "C" void kernel_launch(void* const* d_in, const int* in_sizes, int n_in,
                              void* d_out, int out_size, void* d_ws, size_t ws_size,
                              hipStream_t stream) {
    const float* rays_o  = (const float*)d_in[0];
    const float* rays_d  = (const float*)d_in[1];
    const float* bg      = (const float*)d_in[2];
    const float* p01     = (const float*)d_in[3];
    const float* p02     = (const float*)d_in[4];
    const float* p12     = (const float*)d_in[5];
    const float* feats   = (const float*)d_in[6];
    const float* w1      = (const float*)d_in[7];
    const float* b1      = (const float*)d_in[8];
    const float* w2      = (const float*)d_in[9];
    const float* b2      = (const float*)d_in[10];
    const float* wc1     = (const float*)d_in[11];
    const float* bc1     = (const float*)d_in[12];
    const float* wc2     = (const float*)d_in[13];
    const float* bc2     = (const float*)d_in[14];
    const float* aabb    = (const float*)d_in[15];
    float* out = (float*)d_out;

    const int use_ws = (ws_size >= 6144 * sizeof(u16)) ? 1 : 0;
    u16* wsb = (u16*)d_ws;
    if (use_ws) {
        prep_weights<<<24, 256, 0, stream>>>(w1, wc1, w2, wc2, wsb);
    }
    nerf_mfma<<<NRAYS, 256, 0, stream>>>(rays_o, rays_d, bg, p01, p02, p12, feats,
                                         w1, b1, w2, b2, wc1, bc1, wc2, bc2, aabb, out,
                                         wsb, use_ws);
}

// Round 10
// 99.850 us; speedup vs baseline: 1.6010x; 1.4534x over previous
//
#include <hip/hip_runtime.h>

#define NS 128
#define NRAYS 8192

typedef unsigned short u16;
typedef unsigned int   u32;
typedef unsigned short u16x8 __attribute__((ext_vector_type(8)));
typedef __bf16 b16x8 __attribute__((ext_vector_type(8)));
typedef float f32x4 __attribute__((ext_vector_type(4)));
typedef _Float16 h16x2 __attribute__((ext_vector_type(2)));
typedef unsigned int u32x4 __attribute__((ext_vector_type(4)));
typedef unsigned int u32x2 __attribute__((ext_vector_type(2)));
typedef float f32x2u __attribute__((ext_vector_type(2), aligned(4)));

__device__ __forceinline__ float clampf(float x, float lo, float hi) {
    return fminf(fmaxf(x, lo), hi);
}

__device__ __forceinline__ u16 f2bf(float f) {
    return __builtin_bit_cast(u16, (__bf16)f);
}

// pack two f32 -> bf16 pair in one u32 (lo in bits 0-15)
__device__ __forceinline__ u32 pk2bf(float lo, float hi) {
    return (u32)f2bf(lo) | ((u32)f2bf(hi) << 16);
}

__device__ __forceinline__ u32 pkh(float a, float b) {
    h16x2 v; v[0] = (_Float16)a; v[1] = (_Float16)b;
    return __builtin_bit_cast(u32, v);
}
__device__ __forceinline__ float2 uph(u32 u) {
    h16x2 v = __builtin_bit_cast(h16x2, u);
    return make_float2((float)v[0], (float)v[1]);
}

__device__ __forceinline__ f32x4 mfma_bf16(u16x8 a, u16x8 b, f32x4 c) {
    return __builtin_amdgcn_mfma_f32_16x16x32_bf16(
        __builtin_bit_cast(b16x8, a), __builtin_bit_cast(b16x8, b), c, 0, 0, 0);
}

// swizzled u16-index into a [16][64] tile stored [sample][dim]:
// XOR sample bits into byte bits 4-6 so 16-lane column reads spread banks.
// 8-u16 blocks stay intact (b64 writes are 4-aligned, b128 reads 8-aligned).
#define TSW(n, k) ((((n) * 64) + (k)) ^ (((n) & 7) << 3))

__device__ __forceinline__ void plane_interp(const float* __restrict__ g,
                                             float ca, float cb, float o[3]) {
    float pa = clampf((ca + 1.f) * (0.5f * 127.f), 0.f, 127.f);
    float pb = clampf((cb + 1.f) * (0.5f * 127.f), 0.f, 127.f);
    int la = (int)pa; if (la > 126) la = 126;
    int lb = (int)pb; if (lb > 126) lb = 126;
    float fa = pa - (float)la, fb = pb - (float)lb;
    const float* p = g + la * 128 + lb;
#pragma unroll
    for (int c = 0; c < 3; ++c) {
        const float* q = p + c * 16384;
        f32x2u q0 = *(const f32x2u*)q;
        f32x2u q1 = *(const f32x2u*)(q + 128);
        float top = fmaf(q0[1] - q0[0], fb, q0[0]);
        float bot = fmaf(q1[1] - q1[0], fb, q1[0]);
        o[c] = fmaf(bot - top, fa, top);
    }
}

// ---- prep: pack weight A-fragments (bf16, per-lane layout) into workspace ----
// A-frag value[lane][j] = M[k = (lane>>4)*8+j][idx = lane&15]. wc1 rows are
// PERMUTED to cin' = [so0(zeroed), so1..so15, dx,dy,dz, 0-pad] ordering.
// layout (u16x8 units): [0,256) AW1 (nb*64+lane), [256,512) AWc1',
//                       [512,640) AW2 (ks*64+lane), [640,768) AWc2
__global__ __launch_bounds__(256)
void prep_weights(const float* __restrict__ w1, const float* __restrict__ wc1,
                  const float* __restrict__ w2, const float* __restrict__ wc2,
                  u16* __restrict__ wsb)
{
    int idx = blockIdx.x * 256 + threadIdx.x;   // 0..6143
    if (idx >= 6144) return;
    int lane = (idx >> 3) & 63;
    int j = idx & 7;
    int c16 = lane & 15, kg = lane >> 4;
    float v;
    if (idx < 2048) {                       // AW1
        int nb = idx >> 9;
        int k = kg * 8 + j;
        v = w1[k * 64 + nb * 16 + c16];
    } else if (idx < 4096) {                // AWc1' (permuted rows)
        int nb = (idx - 2048) >> 9;
        int k = kg * 8 + j;                 // cin' row
        if (k == 0)       v = 0.f;
        else if (k < 16)  v = wc1[(k + 2) * 64 + nb * 16 + c16];
        else if (k < 19)  v = wc1[(k - 16) * 64 + nb * 16 + c16];
        else              v = 0.f;
    } else if (idx < 5120) {                // AW2
        int ks = (idx - 4096) >> 9;
        int k = ks * 32 + kg * 8 + j;
        v = w2[k * 16 + c16];
    } else {                                // AWc2 (M padded 3->16)
        int ks = (idx - 5120) >> 9;
        int k = ks * 32 + kg * 8 + j;
        v = (c16 < 3) ? wc2[k * 3 + c16] : 0.f;
    }
    wsb[idx] = f2bf(v);
}

// block = 4 rays, 4 waves, 1 wave = 1 ray, 8 chunks of 16 samples per wave.
// Barrier-free (all LDS regions are per-wave). All GEMMs operand-swapped
// (weights = A-operand, bias = C-operand). h/h2 transposes share ONE per-wave
// [16][64] tile (4x ds_write_b64 + 2x ds_read_b128, swizzled); cin is built
// by 4 shuffles (no LDS tile).
__global__ __launch_bounds__(256)
void nerf_mfma(const float* __restrict__ rays_o,
               const float* __restrict__ rays_d,
               const float* __restrict__ bg_color,
               const float* __restrict__ plane01,
               const float* __restrict__ plane02,
               const float* __restrict__ plane12,
               const float* __restrict__ features,
               const float* __restrict__ w1, const float* __restrict__ b1,
               const float* __restrict__ w2, const float* __restrict__ b2,
               const float* __restrict__ wc1, const float* __restrict__ bc1,
               const float* __restrict__ wc2, const float* __restrict__ bc2,
               const float* __restrict__ aabb,
               float* __restrict__ out,
               const u16* __restrict__ wsb, int use_ws)
{
    __shared__ __align__(16) u32x4 s_cw[4][128];     // trilinear corner weights
    __shared__ u32   s_fb[4][128];                   // cell base offsets
    __shared__ __align__(16) u16  s_tile[4][16 * 64];// per-wave h/h2 transpose tile
    __shared__ float s_tau[4][128];
    __shared__ float s_rgb[4][3][128];

    const int tid  = threadIdx.x;
    const int wv   = tid >> 6;
    const int lane = tid & 63;
    const int c16  = lane & 15;
    const int kg   = lane >> 4;
    const int ray  = blockIdx.x * 4 + wv;
    const int sA   = c16 + 16 * ((2 * kg) & 3);
    const int sB   = c16 + 16 * ((2 * kg + 1) & 3);

    // ---- weight A-fragments (VGPR-resident) ----
    u16x8 AW1[4], AWc1[4], AW2[2], AWc2[2];
    if (use_ws) {
        const u16x8* wf = (const u16x8*)wsb;
#pragma unroll
        for (int nb = 0; nb < 4; ++nb) {
            AW1[nb]  = wf[nb * 64 + lane];
            AWc1[nb] = wf[256 + nb * 64 + lane];
        }
#pragma unroll
        for (int ks = 0; ks < 2; ++ks) {
            AW2[ks]  = wf[512 + ks * 64 + lane];
            AWc2[ks] = wf[640 + ks * 64 + lane];
        }
    } else {
#pragma unroll
        for (int nb = 0; nb < 4; ++nb)
#pragma unroll
            for (int j = 0; j < 8; ++j) {
                int k = kg * 8 + j;
                AW1[nb][j] = f2bf(w1[k * 64 + nb * 16 + c16]);
                float v;
                if (k == 0)       v = 0.f;
                else if (k < 16)  v = wc1[(k + 2) * 64 + nb * 16 + c16];
                else if (k < 19)  v = wc1[(k - 16) * 64 + nb * 16 + c16];
                else              v = 0.f;
                AWc1[nb][j] = f2bf(v);
            }
#pragma unroll
        for (int ks = 0; ks < 2; ++ks)
#pragma unroll
            for (int j = 0; j < 8; ++j) {
                int k = ks * 32 + kg * 8 + j;
                AW2[ks][j]  = f2bf(w2[k * 16 + c16]);
                AWc2[ks][j] = f2bf(c16 < 3 ? wc2[k * 3 + c16] : 0.f);
            }
    }
    // biases as MFMA C-operands: C row = kg*4+q
    f32x4 b1v4[4], bc1v4[4];
#pragma unroll
    for (int nb = 0; nb < 4; ++nb) {
        b1v4[nb]  = *(const f32x4*)(b1  + nb * 16 + kg * 4);
        bc1v4[nb] = *(const f32x4*)(bc1 + nb * 16 + kg * 4);
    }
    f32x4 b2v4 = *(const f32x4*)(b2 + kg * 4);
    f32x4 bc2v4; bc2v4[0] = bc2v4[1] = bc2v4[2] = bc2v4[3] = 0.f;
    if (kg == 0) { bc2v4[0] = bc2[0]; bc2v4[1] = bc2[1]; bc2v4[2] = bc2[2]; }

    // ---- per-ray setup ----
    float ox = rays_o[ray * 3 + 0], oy = rays_o[ray * 3 + 1], oz = rays_o[ray * 3 + 2];
    float dx = rays_d[ray * 3 + 0], dy = rays_d[ray * 3 + 1], dz = rays_d[ray * 3 + 2];
    float rn = rsqrtf(dx * dx + dy * dy + dz * dz);
    dx *= rn; dy *= rn; dz *= rn;

    float lo0 = aabb[0], lo1 = aabb[1], lo2 = aabb[2];
    float hi0 = aabb[3], hi1 = aabb[4], hi2 = aabb[5];

    float invx = 1.f / dx, invy = 1.f / dy, invz = 1.f / dz;
    float tx0 = (lo0 - ox) * invx, tx1 = (hi0 - ox) * invx;
    float ty0 = (lo1 - oy) * invy, ty1 = (hi1 - oy) * invy;
    float tz0 = (lo2 - oz) * invz, tz1 = (hi2 - oz) * invz;
    float tnear = fmaxf(fmaxf(fminf(tx0, tx1), fminf(ty0, ty1)), fminf(tz0, tz1));
    tnear = fmaxf(tnear, 0.f);
    float tfar = fminf(fminf(fmaxf(tx0, tx1), fmaxf(ty0, ty1)), fmaxf(tz0, tz1));
    tfar = fmaxf(tfar, tnear);
    float delta = (tfar - tnear) * (1.f / (float)NS);

    // dir constants for cin' rows 16..18 (kg==2 k-slice)
    const u32 dir01 = pk2bf(dx, dy);
    const u32 dir2z = pk2bf(dz, 0.f);

    // ---- coordinate phase: this wave, 2 samples per lane ----
#pragma unroll
    for (int i = 0; i < 2; ++i) {
        int s = i * 64 + lane;
        float t = tnear + delta * ((float)s + 0.5f);
        float px = ox + dx * t, py = oy + dy * t, pz = oz + dz * t;
        px = (px - lo0) * (2.f / (hi0 - lo0)) - 1.f;
        py = (py - lo1) * (2.f / (hi1 - lo1)) - 1.f;
        pz = (pz - lo2) * (2.f / (hi2 - lo2)) - 1.f;

        float p01[3], p02[3], p12[3];
        plane_interp(plane01, px, py, p01);
        plane_interp(plane02, px, pz, p02);
        plane_interp(plane12, py, pz, p12);
        float gx = p01[0] * p02[0] * p12[0];
        float gy = p01[1] * p02[1] * p12[1];
        float gz = p01[2] * p02[2] * p12[2];

        float qx = clampf((gx + 1.f) * (0.5f * 63.f), 0.f, 63.f);
        float qy = clampf((gy + 1.f) * (0.5f * 63.f), 0.f, 63.f);
        float qz = clampf((gz + 1.f) * (0.5f * 63.f), 0.f, 63.f);
        int ixg = (int)qx; if (ixg > 62) ixg = 62;
        int iyg = (int)qy; if (iyg > 62) iyg = 62;
        int izg = (int)qz; if (izg > 62) izg = 62;
        float fx = qx - (float)ixg, fy = qy - (float)iyg, fz = qz - (float)izg;
        float wx0 = 1.f - fx, wy0 = 1.f - fy, wz0 = 1.f - fz;
        u32x4 cw;
        cw[0] = pkh(wx0 * wy0 * wz0, wx0 * wy0 * fz);
        cw[1] = pkh(wx0 * fy  * wz0, wx0 * fy  * fz);
        cw[2] = pkh(fx  * wy0 * wz0, fx  * wy0 * fz);
        cw[3] = pkh(fx  * fy  * wz0, fx  * fy  * fz);
        s_cw[wv][s] = cw;
        s_fb[wv][s] = (u32)(ixg * 4096 + iyg * 64 + izg);
    }

    // relu C-regs, pack, b64-store to the swizzled [sample][dim] tile
#define RELUSTORE(ACC, NB) {                                           \
        u32x2 wr_;                                                     \
        wr_[0] = pk2bf(fmaxf((ACC)[0], 0.f), fmaxf((ACC)[1], 0.f));    \
        wr_[1] = pk2bf(fmaxf((ACC)[2], 0.f), fmaxf((ACC)[3], 0.f));    \
        *(u32x2*)&s_tile[wv][TSW(c16, (NB) * 16 + kg * 4)] = wr_; }

    // ---- 8 chunks of 16 samples ----
#pragma unroll 1
    for (int c = 0; c < 8; ++c) {
        u32x4 cwp = s_cw[wv][c * 16 + c16];
        u32 fb = s_fb[wv][c * 16 + c16];
        float2 w0p = uph(cwp[0]);
        float2 w1p = uph(cwp[1]);
        float2 w2p = uph(cwp[2]);
        float2 w3p = uph(cwp[3]);
        const float* fbase = features + fb;

        // gather + trilinear combine -> B-operand (col=sample, k=channel)
        u32x4 a1v;
#pragma unroll
        for (int jj = 0; jj < 4; ++jj) {
            float vv[2];
#pragma unroll
            for (int h = 0; h < 2; ++h) {
                const float* f = fbase + (size_t)(kg * 8 + jj * 2 + h) * 262144;
                f32x2u q0 = *(const f32x2u*)(f);
                f32x2u q1 = *(const f32x2u*)(f + 64);
                f32x2u q2 = *(const f32x2u*)(f + 4096);
                f32x2u q3 = *(const f32x2u*)(f + 4160);
                vv[h] = fmaf(w0p.x, q0[0], fmaf(w0p.y, q0[1],
                        fmaf(w1p.x, q1[0], fmaf(w1p.y, q1[1],
                        fmaf(w2p.x, q2[0], fmaf(w2p.y, q2[1],
                        fmaf(w3p.x, q3[0], w3p.y * q3[1])))))));
            }
            a1v[jj] = pk2bf(vv[0], vv[1]);
        }
        u16x8 a1 = __builtin_bit_cast(u16x8, a1v);

        // GEMM1 swapped: h^T = W1^T @ A1^T (bias via C-operand)
        f32x4 g0 = mfma_bf16(AW1[0], a1, b1v4[0]);
        f32x4 g1 = mfma_bf16(AW1[1], a1, b1v4[1]);
        f32x4 g2 = mfma_bf16(AW1[2], a1, b1v4[2]);
        f32x4 g3 = mfma_bf16(AW1[3], a1, b1v4[3]);

        RELUSTORE(g0, 0); RELUSTORE(g1, 1); RELUSTORE(g2, 2); RELUSTORE(g3, 3);
        u16x8 B2_0 = *(const u16x8*)&s_tile[wv][TSW(c16, kg * 8)];
        u16x8 B2_1 = *(const u16x8*)&s_tile[wv][TSW(c16, 32 + kg * 8)];

        // GEMM2 swapped: so^T = W2^T @ h^T
        f32x4 so = mfma_bf16(AW2[0], B2_0, b2v4);
        so = mfma_bf16(AW2[1], B2_1, so);

        // density (so row 0 -> kg==0, q==0 lanes)
        if (kg == 0) {
            float dens = __expf(clampf(so[0], -15.f, 15.f));
            s_tau[wv][c * 16 + c16] = dens * delta;
        }

        // cin'^T B-fragment via 4-lane shuffle; rows 16..18 = dir, 19..31 = 0
        u32 Q0 = pk2bf(so[0], so[1]);
        u32 Q1 = pk2bf(so[2], so[3]);
        u32x4 ct;
        ct[0] = (u32)__shfl((int)Q0, sA);
        ct[1] = (u32)__shfl((int)Q1, sA);
        ct[2] = (u32)__shfl((int)Q0, sB);
        ct[3] = (u32)__shfl((int)Q1, sB);
        if (kg == 2) { ct[0] = dir01; ct[1] = dir2z; ct[2] = 0u; ct[3] = 0u; }
        if (kg == 3) { ct[0] = 0u; ct[1] = 0u; ct[2] = 0u; ct[3] = 0u; }
        u16x8 bcin = __builtin_bit_cast(u16x8, ct);

        // GEMM3 swapped: h2^T = Wc1'^T @ cin'^T (K=32)
        f32x4 h0 = mfma_bf16(AWc1[0], bcin, bc1v4[0]);
        f32x4 h1 = mfma_bf16(AWc1[1], bcin, bc1v4[1]);
        f32x4 h2 = mfma_bf16(AWc1[2], bcin, bc1v4[2]);
        f32x4 h3 = mfma_bf16(AWc1[3], bcin, bc1v4[3]);

        RELUSTORE(h0, 0); RELUSTORE(h1, 1); RELUSTORE(h2, 2); RELUSTORE(h3, 3);
        u16x8 B4_0 = *(const u16x8*)&s_tile[wv][TSW(c16, kg * 8)];
        u16x8 B4_1 = *(const u16x8*)&s_tile[wv][TSW(c16, 32 + kg * 8)];

        // GEMM4 swapped: rgb^T = Wc2^T @ h2^T
        f32x4 cacc = mfma_bf16(AWc2[0], B4_0, bc2v4);
        cacc = mfma_bf16(AWc2[1], B4_1, cacc);

        if (kg == 0) {
            int si = c * 16 + c16;
            s_rgb[wv][0][si] = 1.f / (1.f + __expf(-cacc[0]));
            s_rgb[wv][1][si] = 1.f / (1.f + __expf(-cacc[1]));
            s_rgb[wv][2][si] = 1.f / (1.f + __expf(-cacc[2]));
        }
    }
#undef RELUSTORE

    // ---- per-ray exponential integration (2 samples per lane) ----
    float t0 = s_tau[wv][lane];
    float t1 = s_tau[wv][64 + lane];
    float x0 = t0, x1 = t1;
#pragma unroll
    for (int off = 1; off < 64; off <<= 1) {
        float y = __shfl_up(x0, off);
        if (lane >= off) x0 += y;
    }
    float tot0 = __shfl(x0, 63);
#pragma unroll
    for (int off = 1; off < 64; off <<= 1) {
        float y = __shfl_up(x1, off);
        if (lane >= off) x1 += y;
    }
    x1 += tot0;

    float w0 = __expf(t0 - x0) * (1.f - __expf(-t0));
    float w1s = __expf(t1 - x1) * (1.f - __expf(-t1));

    float v0 = w0 * s_rgb[wv][0][lane] + w1s * s_rgb[wv][0][64 + lane];
    float v1 = w0 * s_rgb[wv][1][lane] + w1s * s_rgb[wv][1][64 + lane];
    float v2 = w0 * s_rgb[wv][2][lane] + w1s * s_rgb[wv][2][64 + lane];
    float v3 = w0 + w1s;
#pragma unroll
    for (int off = 32; off; off >>= 1) {
        v0 += __shfl_xor(v0, off);
        v1 += __shfl_xor(v1, off);
        v2 += __shfl_xor(v2, off);
        v3 += __shfl_xor(v3, off);
    }
    if (lane == 0) {
        float bg = bg_color[0];
        out[ray * 3 + 0] = v0 + (1.f - v3) * bg;
        out[ray * 3 + 1] = v1 + (1.f - v3) * bg;
        out[ray * 3 + 2] = v2 + (1.f - v3) * bg;
    }
}

extern "C" void kernel_launch(void* const* d_in, const int* in_sizes, int n_in,
                              void* d_out, int out_size, void* d_ws, size_t ws_size,
                              hipStream_t stream) {
    const float* rays_o  = (const float*)d_in[0];
    const float* rays_d  = (const float*)d_in[1];
    const float* bg      = (const float*)d_in[2];
    const float* p01     = (const float*)d_in[3];
    const float* p02     = (const float*)d_in[4];
    const float* p12     = (const float*)d_in[5];
    const float* feats   = (const float*)d_in[6];
    const float* w1      = (const float*)d_in[7];
    const float* b1      = (const float*)d_in[8];
    const float* w2      = (const float*)d_in[9];
    const float* b2      = (const float*)d_in[10];
    const float* wc1     = (const float*)d_in[11];
    const float* bc1     = (const float*)d_in[12];
    const float* wc2     = (const float*)d_in[13];
    const float* bc2     = (const float*)d_in[14];
    const float* aabb    = (const float*)d_in[15];
    float* out = (float*)d_out;

    const int use_ws = (ws_size >= 6144 * sizeof(u16)) ? 1 : 0;
    u16* wsb = (u16*)d_ws;
    if (use_ws) {
        prep_weights<<<24, 256, 0, stream>>>(w1, wc1, w2, wc2, wsb);
    }
    nerf_mfma<<<NRAYS / 4, 256, 0, stream>>>(rays_o, rays_d, bg, p01, p02, p12, feats,
                                             w1, b1, w2, b2, wc1, bc1, wc2, bc2, aabb, out,
                                             wsb, use_ws);
}